// Round 3
// baseline (8263.978 us; speedup 1.0000x reference)
//
#include <hip/hip_runtime.h>
#include <stdint.h>

typedef __attribute__((ext_vector_type(8))) short short8;
typedef __attribute__((ext_vector_type(4))) float f32x4;
typedef __attribute__((ext_vector_type(4))) unsigned short ushort4v;
typedef unsigned long long u64;

__device__ inline unsigned short f2bf(float x) {
  union { float f; unsigned u; } v; v.f = x;
  unsigned r = (v.u + 0x7FFFu + ((v.u >> 16) & 1u)) >> 16;
  return (unsigned short)r;
}
__device__ inline float bf2f(unsigned short b) {
  union { unsigned u; float f; } v; v.u = ((unsigned)b) << 16;
  return v.f;
}

__device__ inline void gload_lds16(const void* g, void* l) {
  __builtin_amdgcn_global_load_lds(
      (const __attribute__((address_space(1))) unsigned int*)g,
      (__attribute__((address_space(3))) unsigned int*)l, 16, 0, 0);
}

// ---------- elementwise helpers ----------
__global__ void k_convert(const float* __restrict__ src, unsigned short* __restrict__ dst, int n4) {
  int i = blockIdx.x * blockDim.x + threadIdx.x;
  if (i < n4) {
    f32x4 v = *(const f32x4*)(src + (size_t)i * 4);
    ushort4v r;
    r.x = f2bf(v.x); r.y = f2bf(v.y); r.z = f2bf(v.z); r.w = f2bf(v.w);
    *(ushort4v*)(dst + (size_t)i * 4) = r;
  }
}

__global__ void k_bias(const float* __restrict__ a, const float* __restrict__ b,
                       float* __restrict__ o, int n) {
  int i = blockIdx.x * blockDim.x + threadIdx.x;
  if (i < n) o[i] = a[i] + b[i];
}

__global__ void k_init(unsigned short* __restrict__ h0, int* __restrict__ flags) {
  int i = blockIdx.x * blockDim.x + threadIdx.x;  // 65536 threads
  h0[i] = 0;                                      // ring slot 0 = h_{-1} = 0
  if (i < 256) flags[i] = 0;
}

// ---------- bf16 GEMM: C = A @ B^T (+bias), A [M,K], B [N,K], all bf16, f32 accum ----------
// MODE 0: C bf16, natural row order (xe).
// MODE 1: C bf16 scattered to gx2[t][gt][b][j]  (t=row&511, b=row>>9, gt=(col&1023)>>2,
//         j=(col>>10)*4+(col&3))  -> per-(t,block) slice is contiguous 2KB.
template <int MODE>
__global__ __launch_bounds__(256) void k_gemm_bt(
    const unsigned short* __restrict__ A,
    const unsigned short* __restrict__ Bm,
    const float* __restrict__ bias,
    unsigned short* __restrict__ C,
    int M, int N, int K) {
  __shared__ unsigned short As[128 * 32];
  __shared__ unsigned short Bs[128 * 32];
  const int tid = threadIdx.x;
  const int m0 = blockIdx.y * 128, n0 = blockIdx.x * 128;
  const int lane = tid & 63, w = tid >> 6;
  const int wm = (w >> 1) * 64, wn = (w & 1) * 64;

  f32x4 acc[4][4] = {};

  const int ar0 = tid >> 2;          // 0..63
  const int ak = (tid & 3) * 8;      // 0,8,16,24
  const unsigned short* Ag0 = A + (size_t)(m0 + ar0) * K + ak;
  const unsigned short* Ag1 = A + (size_t)(m0 + 64 + ar0) * K + ak;
  const unsigned short* Bg0 = Bm + (size_t)(n0 + ar0) * K + ak;
  const unsigned short* Bg1 = Bm + (size_t)(n0 + 64 + ar0) * K + ak;
  unsigned short* Al = As + tid * 8;
  unsigned short* Bl = Bs + tid * 8;

  const int lr = lane & 15, lk = (lane >> 4) * 8;

  for (int k0 = 0; k0 < K; k0 += 32) {
    gload_lds16(Ag0 + k0, Al);
    gload_lds16(Ag1 + k0, Al + 2048);
    gload_lds16(Bg0 + k0, Bl);
    gload_lds16(Bg1 + k0, Bl + 2048);
    __syncthreads();
    short8 a[4], b[4];
#pragma unroll
    for (int i = 0; i < 4; i++) a[i] = *(const short8*)&As[(wm + i * 16 + lr) * 32 + lk];
#pragma unroll
    for (int j = 0; j < 4; j++) b[j] = *(const short8*)&Bs[(wn + j * 16 + lr) * 32 + lk];
#pragma unroll
    for (int i = 0; i < 4; i++)
#pragma unroll
      for (int j = 0; j < 4; j++)
        acc[i][j] = __builtin_amdgcn_mfma_f32_16x16x32_bf16(a[i], b[j], acc[i][j], 0, 0, 0);
    __syncthreads();
  }

  const int lq = (lane >> 4) * 4;
#pragma unroll
  for (int j = 0; j < 4; j++) {
    int col = n0 + wn + j * 16 + lr;
    float bv = bias[col];
#pragma unroll
    for (int i = 0; i < 4; i++) {
      int rowb = m0 + wm + i * 16 + lq;
#pragma unroll
      for (int r = 0; r < 4; r++) {
        int row = rowb + r;
        float v = acc[i][j][r] + bv;
        if (MODE == 1) {
          size_t idx = (size_t)(row & 511) * 262144 + (size_t)((col & 1023) >> 2) * 1024
                     + (size_t)(row >> 9) * 16 + (size_t)((col >> 10) * 4 + (col & 3));
          C[idx] = f2bf(v);
        } else {
          C[(size_t)row * (size_t)N + col] = f2bf(v);
        }
      }
    }
  }
}

// ---------- persistent LSTM recurrence ----------
// 256 blocks x 256 threads, 1 block/CU, co-resident. Block gt owns h-cols
// [gt*4, gt*4+4) (16 gate rows). W_hh slice lives in 128 VGPRs per lane for
// all 512 steps. Cross-block sync: write-through h stores + flag release.
template <int RING>
__global__ __launch_bounds__(256, 1) void k_persist(
    const unsigned short* __restrict__ gx2,   // [512][256][64][16] bf16
    const unsigned short* __restrict__ Whh,   // [4096,1024] bf16
    unsigned short* __restrict__ hring,       // RING slots of [64][1024] bf16
    int* __restrict__ flags,                  // [256]
    float* __restrict__ out,                  // [64][512][1024] f32
    float* __restrict__ hout,                 // [64][1024] f32
    float* __restrict__ cout) {               // [64][1024] f32
  __shared__ u64 GxL[256];    // 2KB: gate bias+input contribution, this (t, block)
  __shared__ float Gs[1024];  // 4KB: gates [64 b][16 j]

  const int tid = threadIdx.x, gt = blockIdx.x;
  const int lane = tid & 63, w = tid >> 6;
  const int lr = lane & 15, hi = lane >> 4;

  // ---- stage W_hh slice into registers: wr[kk] = W[grow(lr)][kk*32 + hi*8 ..+8]
  const int grow = (lr >> 2) * 1024 + gt * 4 + (lr & 3);
  const unsigned short* wbase = Whh + (size_t)grow * 1024 + hi * 8;
  short8 wr[32];
#pragma unroll
  for (int kk = 0; kk < 32; ++kk) wr[kk] = *(const short8*)(wbase + kk * 32);

  // ---- per-thread cell state: thread = (b = tid>>2, q = tid&3)
  const int b_loc = tid >> 2, q = tid & 3;
  const int col = gt * 4 + q;
  float c_reg = 0.f;

  for (int t = 0; t < 512; ++t) {
    // 1. wait for all blocks to have finished step t-1
    while (__hip_atomic_load(&flags[tid], __ATOMIC_RELAXED, __HIP_MEMORY_SCOPE_AGENT) < t) {
      __builtin_amdgcn_s_sleep(1);
    }
    __syncthreads();
    __threadfence_block();  // order: no h loads hoisted above the spin

    // 2. issue gx slice load (consumed after MFMA)
    const u64* gp = (const u64*)(gx2 + (size_t)t * 262144 + (size_t)gt * 1024);
    u64 gv = gp[tid];

    // 3. gates partial = h_{t-1} @ Whh_slice^T  (a from global, b from registers)
    const int rslot = (RING == 2) ? (t & 1) : t;
    const unsigned short* hrow = hring + (size_t)rslot * 65536 + (size_t)(w * 16 + lr) * 1024 + hi * 8;
    f32x4 ac0 = {}, ac1 = {}, ac2 = {}, ac3 = {};
    if (RING == 2) {
#pragma unroll
      for (int kk = 0; kk < 32; ++kk) {
        union { u64 d[2]; short8 s; } u;
        u.d[0] = __hip_atomic_load((const u64*)(hrow + kk * 32), __ATOMIC_RELAXED, __HIP_MEMORY_SCOPE_AGENT);
        u.d[1] = __hip_atomic_load((const u64*)(hrow + kk * 32 + 4), __ATOMIC_RELAXED, __HIP_MEMORY_SCOPE_AGENT);
        if ((kk & 3) == 0) ac0 = __builtin_amdgcn_mfma_f32_16x16x32_bf16(u.s, wr[kk], ac0, 0, 0, 0);
        if ((kk & 3) == 1) ac1 = __builtin_amdgcn_mfma_f32_16x16x32_bf16(u.s, wr[kk], ac1, 0, 0, 0);
        if ((kk & 3) == 2) ac2 = __builtin_amdgcn_mfma_f32_16x16x32_bf16(u.s, wr[kk], ac2, 0, 0, 0);
        if ((kk & 3) == 3) ac3 = __builtin_amdgcn_mfma_f32_16x16x32_bf16(u.s, wr[kk], ac3, 0, 0, 0);
      }
    } else {
#pragma unroll
      for (int kk = 0; kk < 32; ++kk) {
        short8 a = *(const short8*)(hrow + kk * 32);
        if ((kk & 3) == 0) ac0 = __builtin_amdgcn_mfma_f32_16x16x32_bf16(a, wr[kk], ac0, 0, 0, 0);
        if ((kk & 3) == 1) ac1 = __builtin_amdgcn_mfma_f32_16x16x32_bf16(a, wr[kk], ac1, 0, 0, 0);
        if ((kk & 3) == 2) ac2 = __builtin_amdgcn_mfma_f32_16x16x32_bf16(a, wr[kk], ac2, 0, 0, 0);
        if ((kk & 3) == 3) ac3 = __builtin_amdgcn_mfma_f32_16x16x32_bf16(a, wr[kk], ac3, 0, 0, 0);
      }
    }
    f32x4 accs = (ac0 + ac1) + (ac2 + ac3);

    GxL[tid] = gv;
    __syncthreads();

    // 4. gates -> Gs.  acc: col j = lr, batch = w*16 + hi*4 + r
    const unsigned short* gxu = (const unsigned short*)GxL;
#pragma unroll
    for (int r = 0; r < 4; ++r) {
      int bb = w * 16 + hi * 4 + r;
      Gs[bb * 16 + lr] = accs[r] + bf2f(gxu[bb * 16 + lr]);
    }
    __syncthreads();

    // 5. cell update for (b_loc, q)
    float gi = Gs[b_loc * 16 + 0 + q];
    float gf = Gs[b_loc * 16 + 4 + q];
    float gg = Gs[b_loc * 16 + 8 + q];
    float go = Gs[b_loc * 16 + 12 + q];
    float i_ = 1.f / (1.f + __expf(-gi));
    float f_ = 1.f / (1.f + __expf(-gf));
    float g_ = tanhf(gg);
    float o_ = 1.f / (1.f + __expf(-go));
    float cn = f_ * c_reg + i_ * g_;
    float hn = o_ * tanhf(cn);
    c_reg = cn;

    out[((size_t)b_loc * 512 + t) * 1024 + col] = hn;
    if (t == 511) {
      hout[(size_t)b_loc * 1024 + col] = hn;
      cout[(size_t)b_loc * 1024 + col] = cn;
    } else {
      // publish h_t: pack 4 cols (q=0..3) into one u64, write-through store
      unsigned hu = f2bf(hn);
      unsigned v0 = __shfl(hu, (lane & ~3) + 0);
      unsigned v1 = __shfl(hu, (lane & ~3) + 1);
      unsigned v2 = __shfl(hu, (lane & ~3) + 2);
      unsigned v3 = __shfl(hu, (lane & ~3) + 3);
      if ((lane & 3) == 0) {
        u64 pack = (u64)(v0 & 0xFFFF) | ((u64)(v1 & 0xFFFF) << 16)
                 | ((u64)(v2 & 0xFFFF) << 32) | ((u64)(v3 & 0xFFFF) << 48);
        int wslot = (RING == 2) ? ((t + 1) & 1) : (t + 1);
        u64* hp = (u64*)(hring + (size_t)wslot * 65536 + (size_t)b_loc * 1024 + gt * 4);
        __hip_atomic_store(hp, pack, __ATOMIC_RELAXED, __HIP_MEMORY_SCOPE_AGENT);
      }
      __threadfence_block();  // drain this wave's stores (vmcnt 0)
      __syncthreads();        // all waves drained
      if (tid == 0)
        __hip_atomic_store(&flags[gt], t + 1, __ATOMIC_RELEASE, __HIP_MEMORY_SCOPE_AGENT);
    }
  }
}

extern "C" void kernel_launch(void* const* d_in, const int* in_sizes, int n_in,
                              void* d_out, int out_size, void* d_ws, size_t ws_size,
                              hipStream_t stream) {
  const float* x = (const float*)d_in[0];
  const float* W_emb = (const float*)d_in[1];
  const float* b_emb = (const float*)d_in[2];
  const float* W_ih = (const float*)d_in[3];
  const float* W_hh = (const float*)d_in[4];
  const float* b_ih = (const float*)d_in[5];
  const float* b_hh = (const float*)d_in[6];

  char* ws = (char*)d_ws;
  unsigned short* x_bf    = (unsigned short*)(ws + 0);           // 16,777,216 B
  unsigned short* Wemb_bf = (unsigned short*)(ws + 16777216);    // 262,144 B
  unsigned short* Wih_bf  = (unsigned short*)(ws + 17039360);    // 4,194,304 B
  unsigned short* Whh_bf  = (unsigned short*)(ws + 21233664);    // 8,388,608 B
  float* bias_sum         = (float*)(ws + 29622272);             // 16,384 B
  unsigned short* xe      = (unsigned short*)(ws + 29638656);    // 33,554,432 B
  unsigned short* gx2     = (unsigned short*)(ws + 63193088);    // 268,435,456 B
  int* flags              = (int*)(ws + 331628544);              // 4,096 B (padded)
  unsigned short* hring   = (unsigned short*)(ws + 331632640);   // RING*131,072 B

  const size_t need_ring = 331632640ull + 512ull * 131072ull;    // ~398.7 MB
  const bool big = (ws_size >= need_ring);

  float* out = (float*)d_out;
  float* hout = out + (size_t)64 * 512 * 1024;
  float* cout = hout + 65536;

  k_convert<<<8192, 256, 0, stream>>>(x, x_bf, 2097152);
  k_convert<<<128, 256, 0, stream>>>(W_emb, Wemb_bf, 32768);
  k_convert<<<2048, 256, 0, stream>>>(W_ih, Wih_bf, 524288);
  k_convert<<<4096, 256, 0, stream>>>(W_hh, Whh_bf, 1048576);
  k_bias<<<16, 256, 0, stream>>>(b_ih, b_hh, bias_sum, 4096);
  k_init<<<256, 256, 0, stream>>>(hring, flags);

  // xe = x @ W_emb^T + b_emb : M=32768, N=512, K=256
  k_gemm_bt<0><<<dim3(4, 256), 256, 0, stream>>>(x_bf, Wemb_bf, b_emb, xe, 32768, 512, 256);
  // gx = xe @ W_ih^T + (b_ih+b_hh), scattered to [t][gt][b][j]
  k_gemm_bt<1><<<dim3(32, 256), 256, 0, stream>>>(xe, Wih_bf, bias_sum, gx2, 32768, 4096, 512);

  if (big)
    k_persist<512><<<256, 256, 0, stream>>>(gx2, Whh_bf, hring, flags, out, hout, cout);
  else
    k_persist<2><<<256, 256, 0, stream>>>(gx2, Whh_bf, hring, flags, out, hout, cout);
}

// Round 5
// 4335.361 us; speedup vs baseline: 1.9062x; 1.9062x over previous
//
#include <hip/hip_runtime.h>
#include <stdint.h>

typedef __attribute__((ext_vector_type(8))) short short8;
typedef __attribute__((ext_vector_type(4))) float f32x4;
typedef __attribute__((ext_vector_type(4))) unsigned short ushort4v;
typedef unsigned long long u64;

__device__ inline unsigned short f2bf(float x) {
  union { float f; unsigned u; } v; v.f = x;
  unsigned r = (v.u + 0x7FFFu + ((v.u >> 16) & 1u)) >> 16;
  return (unsigned short)r;
}
__device__ inline float bf2f(unsigned short b) {
  union { unsigned u; float f; } v; v.u = ((unsigned)b) << 16;
  return v.f;
}

__device__ inline void gload_lds16(const void* g, void* l) {
  __builtin_amdgcn_global_load_lds(
      (const __attribute__((address_space(1))) unsigned int*)g,
      (__attribute__((address_space(3))) unsigned int*)l, 16, 0, 0);
}

// ---------- elementwise helpers ----------
__global__ void k_convert(const float* __restrict__ src, unsigned short* __restrict__ dst, int n4) {
  int i = blockIdx.x * blockDim.x + threadIdx.x;
  if (i < n4) {
    f32x4 v = *(const f32x4*)(src + (size_t)i * 4);
    ushort4v r;
    r.x = f2bf(v.x); r.y = f2bf(v.y); r.z = f2bf(v.z); r.w = f2bf(v.w);
    *(ushort4v*)(dst + (size_t)i * 4) = r;
  }
}

__global__ void k_bias(const float* __restrict__ a, const float* __restrict__ b,
                       float* __restrict__ o, int n) {
  int i = blockIdx.x * blockDim.x + threadIdx.x;
  if (i < n) o[i] = a[i] + b[i];
}

__global__ void k_init(unsigned short* __restrict__ h0, int* __restrict__ flags) {
  int i = blockIdx.x * blockDim.x + threadIdx.x;  // 65536 threads
  h0[i] = 0;                                      // ring slot 0 = h_{-1} = 0
  if (i < 256) flags[i] = 0;
}

// ---------- bf16 GEMM: C = A @ B^T (+bias), A [M,K], B [N,K], all bf16, f32 accum ----------
// MODE 0: C bf16, natural row order (xe).
// MODE 1: C bf16 scattered to gx3[t][gt][w][hi][j][r]:
//   t=row&511, b=row>>9 -> w=b>>4, hi=(b>>2)&3, r=b&3; gt=(col&1023)>>2, j=(col>>10)*4+(col&3)
//   -> per-(t,gt) slice is contiguous 2KB and thread tid's u64 = its 4 MFMA acc lanes.
template <int MODE>
__global__ __launch_bounds__(256) void k_gemm_bt(
    const unsigned short* __restrict__ A,
    const unsigned short* __restrict__ Bm,
    const float* __restrict__ bias,
    unsigned short* __restrict__ C,
    int M, int N, int K) {
  __shared__ unsigned short As[128 * 32];
  __shared__ unsigned short Bs[128 * 32];
  const int tid = threadIdx.x;
  const int m0 = blockIdx.y * 128, n0 = blockIdx.x * 128;
  const int lane = tid & 63, w = tid >> 6;
  const int wm = (w >> 1) * 64, wn = (w & 1) * 64;

  f32x4 acc[4][4] = {};

  const int ar0 = tid >> 2;          // 0..63
  const int ak = (tid & 3) * 8;      // 0,8,16,24
  const unsigned short* Ag0 = A + (size_t)(m0 + ar0) * K + ak;
  const unsigned short* Ag1 = A + (size_t)(m0 + 64 + ar0) * K + ak;
  const unsigned short* Bg0 = Bm + (size_t)(n0 + ar0) * K + ak;
  const unsigned short* Bg1 = Bm + (size_t)(n0 + 64 + ar0) * K + ak;
  unsigned short* Al = As + tid * 8;
  unsigned short* Bl = Bs + tid * 8;

  const int lr = lane & 15, lk = (lane >> 4) * 8;

  for (int k0 = 0; k0 < K; k0 += 32) {
    gload_lds16(Ag0 + k0, Al);
    gload_lds16(Ag1 + k0, Al + 2048);
    gload_lds16(Bg0 + k0, Bl);
    gload_lds16(Bg1 + k0, Bl + 2048);
    __syncthreads();
    short8 a[4], b[4];
#pragma unroll
    for (int i = 0; i < 4; i++) a[i] = *(const short8*)&As[(wm + i * 16 + lr) * 32 + lk];
#pragma unroll
    for (int j = 0; j < 4; j++) b[j] = *(const short8*)&Bs[(wn + j * 16 + lr) * 32 + lk];
#pragma unroll
    for (int i = 0; i < 4; i++)
#pragma unroll
      for (int j = 0; j < 4; j++)
        acc[i][j] = __builtin_amdgcn_mfma_f32_16x16x32_bf16(a[i], b[j], acc[i][j], 0, 0, 0);
    __syncthreads();
  }

  const int lq = (lane >> 4) * 4;
#pragma unroll
  for (int j = 0; j < 4; j++) {
    int col = n0 + wn + j * 16 + lr;
    float bv = bias[col];
#pragma unroll
    for (int i = 0; i < 4; i++) {
      int rowb = m0 + wm + i * 16 + lq;
#pragma unroll
      for (int r = 0; r < 4; r++) {
        int row = rowb + r;
        float v = acc[i][j][r] + bv;
        if (MODE == 1) {
          int t = row & 511, bb = row >> 9;
          int gtb = (col & 1023) >> 2, jj = (col >> 10) * 4 + (col & 3);
          size_t idx = (size_t)t * 262144 + (size_t)gtb * 1024
                     + (size_t)(bb >> 4) * 256 + (size_t)((bb >> 2) & 3) * 64
                     + (size_t)jj * 4 + (size_t)(bb & 3);
          C[idx] = f2bf(v);
        } else {
          C[(size_t)row * (size_t)N + col] = f2bf(v);
        }
      }
    }
  }
}

// ---------- persistent LSTM recurrence ----------
// 256 blocks x 256 threads, 1 block/CU, co-resident. Block gt owns h-cols
// [gt*4, gt*4+4) (16 gate rows). W_hh slice in registers. Sync per step:
// write-through h stores -> vmcnt drain (inside __syncthreads) -> RELAXED flag store;
// consumers: wave0-only poll of all 256 flags -> barrier.
template <int RING>
__global__ __launch_bounds__(256, 1) void k_persist(
    const unsigned short* __restrict__ gx3,   // [512][256][64][16] bf16 (persist layout)
    const unsigned short* __restrict__ Whh,   // [4096,1024] bf16
    unsigned short* __restrict__ hring,       // RING slots of [64][1024] bf16
    int* __restrict__ flags,                  // [256]
    float* __restrict__ out,                  // [64][512][1024] f32
    float* __restrict__ hout,                 // [64][1024] f32
    float* __restrict__ cout) {               // [64][1024] f32
  __shared__ float Gs[1024];  // 4KB: gates [64 b][16 j]

  const int tid = threadIdx.x, gt = blockIdx.x;
  const int lane = tid & 63, w = tid >> 6;
  const int lr = lane & 15, hi = lane >> 4;

  // ---- W_hh slice: wr[kk] = W[grow(lr)][kk*32 + hi*8 ..+8]
  const int grow = (lr >> 2) * 1024 + gt * 4 + (lr & 3);
  const unsigned short* wbase = Whh + (size_t)grow * 1024 + hi * 8;
  short8 wr[32];
#pragma unroll
  for (int kk = 0; kk < 32; ++kk) wr[kk] = *(const short8*)(wbase + kk * 32);

  // ---- per-thread cell state: thread = (b = tid>>2, q = tid&3)
  const int b_loc = tid >> 2, q = tid & 3;
  const int col = gt * 4 + q;
  float c_reg = 0.f;

  // gx double buffer (independent of h -> prefetchable).
  // NOTE: per-t stride = 262144 bf16 = 65536 u64 (R4 bug: was 32768).
  const u64* gbase = (const u64*)(gx3 + (size_t)gt * 1024);
  u64 gv = gbase[tid];  // t = 0

  for (int t = 0; t < 512; ++t) {
    // 1. wait for all blocks to have published h slot t (wave 0 polls)
    if (w == 0) {
      const u64* fp = (const u64*)(flags + lane * 4);
      for (;;) {
        u64 f01 = __hip_atomic_load(fp, __ATOMIC_RELAXED, __HIP_MEMORY_SCOPE_AGENT);
        u64 f23 = __hip_atomic_load(fp + 1, __ATOMIC_RELAXED, __HIP_MEMORY_SCOPE_AGENT);
        bool ok = ((int)f01 >= t) && ((int)(f01 >> 32) >= t) &&
                  ((int)f23 >= t) && ((int)(f23 >> 32) >= t);
        if (__all(ok)) break;
        __builtin_amdgcn_s_sleep(1);
      }
    }
    __syncthreads();
    __builtin_amdgcn_sched_barrier(0);

    // 2. gates partial = h_{t-1} @ Whh_slice^T
    const int rslot = (RING == 2) ? (t & 1) : t;
    const unsigned short* hrow = hring + (size_t)rslot * 65536 + (size_t)(w * 16 + lr) * 1024 + hi * 8;
    f32x4 ac0 = {}, ac1 = {}, ac2 = {}, ac3 = {};
    if (RING == 2) {
#pragma unroll
      for (int kk = 0; kk < 32; ++kk) {
        union { u64 d[2]; short8 s; } u;
        u.d[0] = __hip_atomic_load((const u64*)(hrow + kk * 32), __ATOMIC_RELAXED, __HIP_MEMORY_SCOPE_AGENT);
        u.d[1] = __hip_atomic_load((const u64*)(hrow + kk * 32 + 4), __ATOMIC_RELAXED, __HIP_MEMORY_SCOPE_AGENT);
        if ((kk & 3) == 0) ac0 = __builtin_amdgcn_mfma_f32_16x16x32_bf16(u.s, wr[kk], ac0, 0, 0, 0);
        if ((kk & 3) == 1) ac1 = __builtin_amdgcn_mfma_f32_16x16x32_bf16(u.s, wr[kk], ac1, 0, 0, 0);
        if ((kk & 3) == 2) ac2 = __builtin_amdgcn_mfma_f32_16x16x32_bf16(u.s, wr[kk], ac2, 0, 0, 0);
        if ((kk & 3) == 3) ac3 = __builtin_amdgcn_mfma_f32_16x16x32_bf16(u.s, wr[kk], ac3, 0, 0, 0);
      }
    } else {
#pragma unroll
      for (int kk = 0; kk < 32; ++kk) {
        short8 a = *(const short8*)(hrow + kk * 32);
        if ((kk & 3) == 0) ac0 = __builtin_amdgcn_mfma_f32_16x16x32_bf16(a, wr[kk], ac0, 0, 0, 0);
        if ((kk & 3) == 1) ac1 = __builtin_amdgcn_mfma_f32_16x16x32_bf16(a, wr[kk], ac1, 0, 0, 0);
        if ((kk & 3) == 2) ac2 = __builtin_amdgcn_mfma_f32_16x16x32_bf16(a, wr[kk], ac2, 0, 0, 0);
        if ((kk & 3) == 3) ac3 = __builtin_amdgcn_mfma_f32_16x16x32_bf16(a, wr[kk], ac3, 0, 0, 0);
      }
    }
    f32x4 accs = (ac0 + ac1) + (ac2 + ac3);

    // 3. add gx (thread-local: gv element r matches acc reg r), stage Gs
#pragma unroll
    for (int r = 0; r < 4; ++r) {
      int bb = w * 16 + hi * 4 + r;
      Gs[bb * 16 + lr] = accs[r] + bf2f((unsigned short)(gv >> (16 * r)));
    }
    // prefetch next step's gx while Gs/cell/publish run (stride = 65536 u64 per t)
    if (t < 511) gv = gbase[(size_t)(t + 1) * 65536 + tid];
    __syncthreads();

    // 4. cell update for (b_loc, q)
    float gi = Gs[b_loc * 16 + 0 + q];
    float gf = Gs[b_loc * 16 + 4 + q];
    float gg = Gs[b_loc * 16 + 8 + q];
    float go = Gs[b_loc * 16 + 12 + q];
    float i_ = 1.f / (1.f + __expf(-gi));
    float f_ = 1.f / (1.f + __expf(-gf));
    float g_ = tanhf(gg);
    float o_ = 1.f / (1.f + __expf(-go));
    float cn = f_ * c_reg + i_ * g_;
    float hn = o_ * tanhf(cn);
    c_reg = cn;

    __builtin_nontemporal_store(hn, &out[((size_t)b_loc * 512 + t) * 1024 + col]);
    if (t == 511) {
      hout[(size_t)b_loc * 1024 + col] = hn;
      cout[(size_t)b_loc * 1024 + col] = cn;
    } else {
      // publish h_t: pack 4 cols (q=0..3) into one u64, write-through store
      unsigned hu = f2bf(hn);
      unsigned v0 = __shfl(hu, (lane & ~3) + 0);
      unsigned v1 = __shfl(hu, (lane & ~3) + 1);
      unsigned v2 = __shfl(hu, (lane & ~3) + 2);
      unsigned v3 = __shfl(hu, (lane & ~3) + 3);
      if ((lane & 3) == 0) {
        u64 pack = (u64)(v0 & 0xFFFF) | ((u64)(v1 & 0xFFFF) << 16)
                 | ((u64)(v2 & 0xFFFF) << 32) | ((u64)(v3 & 0xFFFF) << 48);
        int wslot = (RING == 2) ? ((t + 1) & 1) : (t + 1);
        u64* hp = (u64*)(hring + (size_t)wslot * 65536 + (size_t)b_loc * 1024 + gt * 4);
        __hip_atomic_store(hp, pack, __ATOMIC_RELAXED, __HIP_MEMORY_SCOPE_AGENT);
      }
      __threadfence_block();  // per-wave ordering before barrier
      __syncthreads();        // vmcnt(0) drain for all waves + block-wide sync
      if (tid == 0)           // RELAXED: no L2 writeback on the critical path
        __hip_atomic_store(&flags[gt], t + 1, __ATOMIC_RELAXED, __HIP_MEMORY_SCOPE_AGENT);
    }
  }
}

extern "C" void kernel_launch(void* const* d_in, const int* in_sizes, int n_in,
                              void* d_out, int out_size, void* d_ws, size_t ws_size,
                              hipStream_t stream) {
  const float* x = (const float*)d_in[0];
  const float* W_emb = (const float*)d_in[1];
  const float* b_emb = (const float*)d_in[2];
  const float* W_ih = (const float*)d_in[3];
  const float* W_hh = (const float*)d_in[4];
  const float* b_ih = (const float*)d_in[5];
  const float* b_hh = (const float*)d_in[6];

  char* ws = (char*)d_ws;
  unsigned short* x_bf    = (unsigned short*)(ws + 0);           // 16,777,216 B
  unsigned short* Wemb_bf = (unsigned short*)(ws + 16777216);    // 262,144 B
  unsigned short* Wih_bf  = (unsigned short*)(ws + 17039360);    // 4,194,304 B
  unsigned short* Whh_bf  = (unsigned short*)(ws + 21233664);    // 8,388,608 B
  float* bias_sum         = (float*)(ws + 29622272);             // 16,384 B
  unsigned short* xe      = (unsigned short*)(ws + 29638656);    // 33,554,432 B
  unsigned short* gx3     = (unsigned short*)(ws + 63193088);    // 268,435,456 B
  int* flags              = (int*)(ws + 331628544);              // 4,096 B (padded)
  unsigned short* hring   = (unsigned short*)(ws + 331632640);   // RING*131,072 B

  const size_t need_ring = 331632640ull + 512ull * 131072ull;    // ~398.7 MB
  const bool big = (ws_size >= need_ring);

  float* out = (float*)d_out;
  float* hout = out + (size_t)64 * 512 * 1024;
  float* cout = hout + 65536;

  k_convert<<<8192, 256, 0, stream>>>(x, x_bf, 2097152);
  k_convert<<<128, 256, 0, stream>>>(W_emb, Wemb_bf, 32768);
  k_convert<<<2048, 256, 0, stream>>>(W_ih, Wih_bf, 524288);
  k_convert<<<4096, 256, 0, stream>>>(W_hh, Whh_bf, 1048576);
  k_bias<<<16, 256, 0, stream>>>(b_ih, b_hh, bias_sum, 4096);
  k_init<<<256, 256, 0, stream>>>(hring, flags);

  // xe = x @ W_emb^T + b_emb : M=32768, N=512, K=256
  k_gemm_bt<0><<<dim3(4, 256), 256, 0, stream>>>(x_bf, Wemb_bf, b_emb, xe, 32768, 512, 256);
  // gx = xe @ W_ih^T + (b_ih+b_hh), scattered to persist layout
  k_gemm_bt<1><<<dim3(32, 256), 256, 0, stream>>>(xe, Wih_bf, bias_sum, gx3, 32768, 4096, 512);

  if (big)
    k_persist<512><<<256, 256, 0, stream>>>(gx3, Whh_bf, hring, flags, out, hout, cout);
  else
    k_persist<2><<<256, 256, 0, stream>>>(gx3, Whh_bf, hring, flags, out, hout, cout);
}

// Round 6
// 3352.877 us; speedup vs baseline: 2.4647x; 1.2930x over previous
//
#include <hip/hip_runtime.h>
#include <stdint.h>

typedef __attribute__((ext_vector_type(8))) short short8;
typedef __attribute__((ext_vector_type(4))) float f32x4;
typedef __attribute__((ext_vector_type(4))) unsigned short ushort4v;
typedef unsigned long long u64;

__device__ inline unsigned short f2bf(float x) {
  union { float f; unsigned u; } v; v.f = x;
  unsigned r = (v.u + 0x7FFFu + ((v.u >> 16) & 1u)) >> 16;
  return (unsigned short)r;
}
__device__ inline float bf2f(unsigned short b) {
  union { unsigned u; float f; } v; v.u = ((unsigned)b) << 16;
  return v.f;
}
__device__ inline float fsig(float x) { return 1.f / (1.f + __expf(-x)); }
__device__ inline float ftanh(float x) { return 2.f / (1.f + __expf(-2.f * x)) - 1.f; }

__device__ inline void gload_lds16(const void* g, void* l) {
  __builtin_amdgcn_global_load_lds(
      (const __attribute__((address_space(1))) unsigned int*)g,
      (__attribute__((address_space(3))) unsigned int*)l, 16, 0, 0);
}

// ---------- elementwise helpers ----------
__global__ void k_convert(const float* __restrict__ src, unsigned short* __restrict__ dst, int n4) {
  int i = blockIdx.x * blockDim.x + threadIdx.x;
  if (i < n4) {
    f32x4 v = *(const f32x4*)(src + (size_t)i * 4);
    ushort4v r;
    r.x = f2bf(v.x); r.y = f2bf(v.y); r.z = f2bf(v.z); r.w = f2bf(v.w);
    *(ushort4v*)(dst + (size_t)i * 4) = r;
  }
}

__global__ void k_bias(const float* __restrict__ a, const float* __restrict__ b,
                       float* __restrict__ o, int n) {
  int i = blockIdx.x * blockDim.x + threadIdx.x;
  if (i < n) o[i] = a[i] + b[i];
}

__global__ void k_init(unsigned short* __restrict__ h0, int* __restrict__ flags) {
  int i = blockIdx.x * blockDim.x + threadIdx.x;  // 65536 threads
  h0[i] = 0;                                      // ring slot 0 = h_{-1} = 0
  if (i < 256) flags[i] = 0;
}

// ---------- bf16 GEMM: C = A @ B^T (+bias), A [M,K], B [N,K], all bf16, f32 accum ----------
// MODE 0: C bf16, natural row order (xe).
// MODE 1: C bf16 scattered to gx3[t][gt][w][hi][j][r] (persist layout).
template <int MODE>
__global__ __launch_bounds__(256) void k_gemm_bt(
    const unsigned short* __restrict__ A,
    const unsigned short* __restrict__ Bm,
    const float* __restrict__ bias,
    unsigned short* __restrict__ C,
    int M, int N, int K) {
  __shared__ unsigned short As[128 * 32];
  __shared__ unsigned short Bs[128 * 32];
  const int tid = threadIdx.x;
  const int m0 = blockIdx.y * 128, n0 = blockIdx.x * 128;
  const int lane = tid & 63, w = tid >> 6;
  const int wm = (w >> 1) * 64, wn = (w & 1) * 64;

  f32x4 acc[4][4] = {};

  const int ar0 = tid >> 2;          // 0..63
  const int ak = (tid & 3) * 8;      // 0,8,16,24
  const unsigned short* Ag0 = A + (size_t)(m0 + ar0) * K + ak;
  const unsigned short* Ag1 = A + (size_t)(m0 + 64 + ar0) * K + ak;
  const unsigned short* Bg0 = Bm + (size_t)(n0 + ar0) * K + ak;
  const unsigned short* Bg1 = Bm + (size_t)(n0 + 64 + ar0) * K + ak;
  unsigned short* Al = As + tid * 8;
  unsigned short* Bl = Bs + tid * 8;

  const int lr = lane & 15, lk = (lane >> 4) * 8;

  for (int k0 = 0; k0 < K; k0 += 32) {
    gload_lds16(Ag0 + k0, Al);
    gload_lds16(Ag1 + k0, Al + 2048);
    gload_lds16(Bg0 + k0, Bl);
    gload_lds16(Bg1 + k0, Bl + 2048);
    __syncthreads();
    short8 a[4], b[4];
#pragma unroll
    for (int i = 0; i < 4; i++) a[i] = *(const short8*)&As[(wm + i * 16 + lr) * 32 + lk];
#pragma unroll
    for (int j = 0; j < 4; j++) b[j] = *(const short8*)&Bs[(wn + j * 16 + lr) * 32 + lk];
#pragma unroll
    for (int i = 0; i < 4; i++)
#pragma unroll
      for (int j = 0; j < 4; j++)
        acc[i][j] = __builtin_amdgcn_mfma_f32_16x16x32_bf16(a[i], b[j], acc[i][j], 0, 0, 0);
    __syncthreads();
  }

  const int lq = (lane >> 4) * 4;
#pragma unroll
  for (int j = 0; j < 4; j++) {
    int col = n0 + wn + j * 16 + lr;
    float bv = bias[col];
#pragma unroll
    for (int i = 0; i < 4; i++) {
      int rowb = m0 + wm + i * 16 + lq;
#pragma unroll
      for (int r = 0; r < 4; r++) {
        int row = rowb + r;
        float v = acc[i][j][r] + bv;
        if (MODE == 1) {
          int t = row & 511, bb = row >> 9;
          int gtb = (col & 1023) >> 2, jj = (col >> 10) * 4 + (col & 3);
          size_t idx = (size_t)t * 262144 + (size_t)gtb * 1024
                     + (size_t)(bb >> 4) * 256 + (size_t)((bb >> 2) & 3) * 64
                     + (size_t)jj * 4 + (size_t)(bb & 3);
          C[idx] = f2bf(v);
        } else {
          C[(size_t)row * (size_t)N + col] = f2bf(v);
        }
      }
    }
  }
}

// ---------- persistent LSTM recurrence ----------
// 256 blocks x 256 threads, 1 block/CU. Block gt owns h-cols [gt*4,gt*4+4).
// W_hh slice pinned in 128 VGPRs via inline-asm loads (compiler cannot
// rematerialize asm -> stays register-resident across the step loop).
template <int RING>
__global__ __launch_bounds__(256, 1) void k_persist(
    const unsigned short* __restrict__ gx3,   // [512][256][64][16] bf16 (persist layout)
    const unsigned short* __restrict__ Whh,   // [4096,1024] bf16
    unsigned short* __restrict__ hring,       // RING slots of [64][1024] bf16
    int* __restrict__ flags,                  // [256]
    float* __restrict__ out,                  // [64][512][1024] f32
    float* __restrict__ hout,                 // [64][1024] f32
    float* __restrict__ cout) {               // [64][1024] f32
  __shared__ float Gs[1024];  // 4KB: gates [64 b][16 j]

  const int tid = threadIdx.x, gt = blockIdx.x;
  const int lane = tid & 63, w = tid >> 6;
  const int lr = lane & 15, hi = lane >> 4;

  // ---- W_hh slice pinned in VGPRs: wr[kk] = W[grow(lr)][kk*32 + hi*8 ..+8]
  const int grow = (lr >> 2) * 1024 + gt * 4 + (lr & 3);
  const unsigned short* wbase = Whh + (size_t)grow * 1024 + hi * 8;
  short8 wr[32];
#pragma unroll
  for (int kk = 0; kk < 32; ++kk) {
    asm volatile("global_load_dwordx4 %0, %1, off"
                 : "=v"(wr[kk]) : "v"(wbase + kk * 32));
  }
  asm volatile("s_waitcnt vmcnt(0)" ::: "memory");
  __builtin_amdgcn_sched_barrier(0);

  // ---- per-thread cell state: thread = (b = tid>>2, q = tid&3)
  const int b_loc = tid >> 2, q = tid & 3;
  const int col = gt * 4 + q;
  float c_reg = 0.f;

  // gx prefetch register (per-t stride = 65536 u64)
  const u64* gbase = (const u64*)(gx3 + (size_t)gt * 1024);
  u64 gv = gbase[tid];  // t = 0

  for (int t = 0; t < 512; ++t) {
    // 1. wait for all blocks to have published h slot t (wave 0 polls)
    if (w == 0) {
      const u64* fp = (const u64*)(flags + lane * 4);
      for (;;) {
        u64 f01 = __hip_atomic_load(fp, __ATOMIC_RELAXED, __HIP_MEMORY_SCOPE_AGENT);
        u64 f23 = __hip_atomic_load(fp + 1, __ATOMIC_RELAXED, __HIP_MEMORY_SCOPE_AGENT);
        bool ok = ((int)f01 >= t) && ((int)(f01 >> 32) >= t) &&
                  ((int)f23 >= t) && ((int)(f23 >> 32) >= t);
        if (__all(ok)) break;
        __builtin_amdgcn_s_sleep(1);
      }
    }
    __syncthreads();
    __builtin_amdgcn_sched_barrier(0);

    // 2. gates partial = h_{t-1} @ Whh_slice^T
    const int rslot = (RING == 2) ? (t & 1) : t;
    const unsigned short* hrow = hring + (size_t)rslot * 65536 + (size_t)(w * 16 + lr) * 1024 + hi * 8;
    f32x4 ac0 = {}, ac1 = {}, ac2 = {}, ac3 = {};
    if (RING == 2) {
#pragma unroll
      for (int kk = 0; kk < 32; ++kk) {
        union { u64 d[2]; short8 s; } u;
        u.d[0] = __hip_atomic_load((const u64*)(hrow + kk * 32), __ATOMIC_RELAXED, __HIP_MEMORY_SCOPE_AGENT);
        u.d[1] = __hip_atomic_load((const u64*)(hrow + kk * 32 + 4), __ATOMIC_RELAXED, __HIP_MEMORY_SCOPE_AGENT);
        if ((kk & 3) == 0) ac0 = __builtin_amdgcn_mfma_f32_16x16x32_bf16(u.s, wr[kk], ac0, 0, 0, 0);
        if ((kk & 3) == 1) ac1 = __builtin_amdgcn_mfma_f32_16x16x32_bf16(u.s, wr[kk], ac1, 0, 0, 0);
        if ((kk & 3) == 2) ac2 = __builtin_amdgcn_mfma_f32_16x16x32_bf16(u.s, wr[kk], ac2, 0, 0, 0);
        if ((kk & 3) == 3) ac3 = __builtin_amdgcn_mfma_f32_16x16x32_bf16(u.s, wr[kk], ac3, 0, 0, 0);
      }
    } else {
#pragma unroll
      for (int kk = 0; kk < 32; ++kk) {
        short8 a = *(const short8*)(hrow + kk * 32);
        if ((kk & 3) == 0) ac0 = __builtin_amdgcn_mfma_f32_16x16x32_bf16(a, wr[kk], ac0, 0, 0, 0);
        if ((kk & 3) == 1) ac1 = __builtin_amdgcn_mfma_f32_16x16x32_bf16(a, wr[kk], ac1, 0, 0, 0);
        if ((kk & 3) == 2) ac2 = __builtin_amdgcn_mfma_f32_16x16x32_bf16(a, wr[kk], ac2, 0, 0, 0);
        if ((kk & 3) == 3) ac3 = __builtin_amdgcn_mfma_f32_16x16x32_bf16(a, wr[kk], ac3, 0, 0, 0);
      }
    }
    f32x4 accs = (ac0 + ac1) + (ac2 + ac3);

    // 3. add gx (thread-local: gv element r matches acc reg r), stage Gs
#pragma unroll
    for (int r = 0; r < 4; ++r) {
      int bb = w * 16 + hi * 4 + r;
      Gs[bb * 16 + lr] = accs[r] + bf2f((unsigned short)(gv >> (16 * r)));
    }
    __syncthreads();

    // 4. cell update for (b_loc, q)
    float gi = Gs[b_loc * 16 + 0 + q];
    float gf = Gs[b_loc * 16 + 4 + q];
    float gg = Gs[b_loc * 16 + 8 + q];
    float go = Gs[b_loc * 16 + 12 + q];
    float i_ = fsig(gi);
    float f_ = fsig(gf);
    float g_ = ftanh(gg);
    float o_ = fsig(go);
    float cn = f_ * c_reg + i_ * g_;
    float hn = o_ * ftanh(cn);
    c_reg = cn;

    if (t == 511) {
      __builtin_nontemporal_store(hn, &out[((size_t)b_loc * 512 + t) * 1024 + col]);
      hout[(size_t)b_loc * 1024 + col] = hn;
      cout[(size_t)b_loc * 1024 + col] = cn;
    } else {
      // publish h_t FIRST: pack 4 cols (q=0..3) into one u64, write-through store
      unsigned hu = f2bf(hn);
      unsigned v0 = __shfl(hu, (lane & ~3) + 0);
      unsigned v1 = __shfl(hu, (lane & ~3) + 1);
      unsigned v2 = __shfl(hu, (lane & ~3) + 2);
      unsigned v3 = __shfl(hu, (lane & ~3) + 3);
      if ((lane & 3) == 0) {
        u64 pack = (u64)(v0 & 0xFFFF) | ((u64)(v1 & 0xFFFF) << 16)
                 | ((u64)(v2 & 0xFFFF) << 32) | ((u64)(v3 & 0xFFFF) << 48);
        int wslot = (RING == 2) ? ((t + 1) & 1) : (t + 1);
        u64* hp = (u64*)(hring + (size_t)wslot * 65536 + (size_t)b_loc * 1024 + gt * 4);
        __hip_atomic_store(hp, pack, __ATOMIC_RELAXED, __HIP_MEMORY_SCOPE_AGENT);
      }
      __threadfence_block();  // per-wave drain of the h store
      __syncthreads();        // all waves drained (barrier implies vmcnt(0))
      if (tid == 0)           // RELAXED flag: no L2 writeback on the critical path
        __hip_atomic_store(&flags[gt], t + 1, __ATOMIC_RELAXED, __HIP_MEMORY_SCOPE_AGENT);
      // out store + next-gx prefetch AFTER the handshake: their latency drains
      // under the next poll/MFMA phase instead of inside the publish fence.
      __builtin_nontemporal_store(hn, &out[((size_t)b_loc * 512 + t) * 1024 + col]);
      gv = gbase[(size_t)(t + 1) * 65536 + tid];
    }
  }
}

extern "C" void kernel_launch(void* const* d_in, const int* in_sizes, int n_in,
                              void* d_out, int out_size, void* d_ws, size_t ws_size,
                              hipStream_t stream) {
  const float* x = (const float*)d_in[0];
  const float* W_emb = (const float*)d_in[1];
  const float* b_emb = (const float*)d_in[2];
  const float* W_ih = (const float*)d_in[3];
  const float* W_hh = (const float*)d_in[4];
  const float* b_ih = (const float*)d_in[5];
  const float* b_hh = (const float*)d_in[6];

  char* ws = (char*)d_ws;
  unsigned short* x_bf    = (unsigned short*)(ws + 0);           // 16,777,216 B
  unsigned short* Wemb_bf = (unsigned short*)(ws + 16777216);    // 262,144 B
  unsigned short* Wih_bf  = (unsigned short*)(ws + 17039360);    // 4,194,304 B
  unsigned short* Whh_bf  = (unsigned short*)(ws + 21233664);    // 8,388,608 B
  float* bias_sum         = (float*)(ws + 29622272);             // 16,384 B
  unsigned short* xe      = (unsigned short*)(ws + 29638656);    // 33,554,432 B
  unsigned short* gx3     = (unsigned short*)(ws + 63193088);    // 268,435,456 B
  int* flags              = (int*)(ws + 331628544);              // 4,096 B (padded)
  unsigned short* hring   = (unsigned short*)(ws + 331632640);   // RING*131,072 B

  const size_t need_ring = 331632640ull + 512ull * 131072ull;    // ~398.7 MB
  const bool big = (ws_size >= need_ring);

  float* out = (float*)d_out;
  float* hout = out + (size_t)64 * 512 * 1024;
  float* cout = hout + 65536;

  k_convert<<<8192, 256, 0, stream>>>(x, x_bf, 2097152);
  k_convert<<<128, 256, 0, stream>>>(W_emb, Wemb_bf, 32768);
  k_convert<<<2048, 256, 0, stream>>>(W_ih, Wih_bf, 524288);
  k_convert<<<4096, 256, 0, stream>>>(W_hh, Whh_bf, 1048576);
  k_bias<<<16, 256, 0, stream>>>(b_ih, b_hh, bias_sum, 4096);
  k_init<<<256, 256, 0, stream>>>(hring, flags);

  // xe = x @ W_emb^T + b_emb : M=32768, N=512, K=256
  k_gemm_bt<0><<<dim3(4, 256), 256, 0, stream>>>(x_bf, Wemb_bf, b_emb, xe, 32768, 512, 256);
  // gx = xe @ W_ih^T + (b_ih+b_hh), scattered to persist layout
  k_gemm_bt<1><<<dim3(32, 256), 256, 0, stream>>>(xe, Wih_bf, bias_sum, gx3, 32768, 4096, 512);

  if (big)
    k_persist<512><<<256, 256, 0, stream>>>(gx3, Whh_bf, hring, flags, out, hout, cout);
  else
    k_persist<2><<<256, 256, 0, stream>>>(gx3, Whh_bf, hring, flags, out, hout, cout);
}